// Round 18
// baseline (64.390 us; speedup 1.0000x reference)
//
#include <hip/hip_runtime.h>
#include <hip/hip_bf16.h>
#include <math.h>

#define NN 768
#define FF 128
#define VV 64
#define RH 16
#define SPLITK 32
#define SEND_PER_KC 24          // 768 / SPLITK
#define NITER 3                 // SEND_PER_KC / 8 senders per iter
#define KSTEPS 384              // 12288 / 32
#define NT_S 8                  // scalar n-tiles (128/16)
#define NT_V 16                 // vector n-tiles (256/16)
#define MB_N 24                 // M-blocks (768/32)

typedef __attribute__((ext_vector_type(8))) short bf16x8_t;
typedef __attribute__((ext_vector_type(4))) float f32x4;

__device__ __forceinline__ float silu_f(float a) {
  return a * __builtin_amdgcn_rcpf(1.0f + __expf(-a));
}

__device__ __forceinline__ short f2bf(float f) {
  __hip_bfloat16 h = __float2bfloat16(f);  // RNE; pairs into v_cvt_pk_bf16_f32
  return __builtin_bit_cast(short, h);
}

__device__ __forceinline__ float bf2f(unsigned short v) {
  return __builtin_bit_cast(float, (unsigned)v << 16);
}

// ---------------------------------------------------------------------------
// Layer-0 fused kernel (R17 verbatim): register-resident moments + node
// update + direct B-fragment emission for layer 1.
// ---------------------------------------------------------------------------
__global__ __launch_bounds__(256) void layer0_kernel(
    const float* __restrict__ x,
    const float* __restrict__ Wr1,    // [16] layer-0
    const float* __restrict__ Wr2s,   // [2][16][128] (both layers)
    const float* __restrict__ Wr2v,   // [2][16][64]
    const float* __restrict__ embed,  // [128]
    const float* __restrict__ Wsv0,   // [128][64] layer-0
    const float* __restrict__ Wss,    // [128][128] layer-0
    const float* __restrict__ Wvs,    // [64][128]  layer-0
    const float* __restrict__ Wvv,    // [64][64]   layer-0
    const float* __restrict__ Wsv1,   // [128][64]  layer-1 (for hsv)
    float* __restrict__ hs,
    float* __restrict__ hv,
    unsigned short* __restrict__ Bs,  // [384*8][64][8] bf16
    unsigned short* __restrict__ Bv)  // [384*16][64][8] bf16
{
  __shared__ float accT[256 * 33];
  __shared__ float red8[8][32];
  __shared__ float fin[64];
  __shared__ float cvs[64];
  __shared__ float as_l[FF];
  __shared__ float av_l[192];
  __shared__ float inv_l[VV];
  __shared__ float hsn[FF];
  __shared__ float hsv_l[VV];
  __shared__ float redn[256];

  const int r   = blockIdx.x;
  const int tid = threadIdx.x;

  if (tid < 64) {
    float a = 0.f;
    #pragma unroll 8
    for (int f = 0; f < FF; ++f) a += embed[f] * Wsv0[f * VV + tid];
    cvs[tid] = a;
  }

  float wr1[RH];
  #pragma unroll
  for (int hh = 0; hh < RH; ++hh) wr1[hh] = Wr1[hh];

  const float xr0 = x[r * 3 + 0], xr1 = x[r * 3 + 1], xr2 = x[r * 3 + 2];

  float acc[64];
  #pragma unroll
  for (int i = 0; i < 64; ++i) acc[i] = 0.f;

  #pragma unroll
  for (int ss = 0; ss < 3; ++ss) {
    const int s = tid + ss * 256;
    const float vx = x[s * 3 + 0] - xr0;
    const float vy = x[s * 3 + 1] - xr1;
    const float vz = x[s * 3 + 2] - xr2;
    const float d  = __builtin_amdgcn_sqrtf(vx * vx + vy * vy + vz * vz);
    const float iv = __builtin_amdgcn_rcpf(d + 1e-8f);
    const float ux = vx * iv, uy = vy * iv, uz = vz * iv;
    #pragma unroll
    for (int h = 0; h < RH; ++h) {
      const float rf = silu_f(d * wr1[h]);
      acc[h * 4 + 0] += rf;
      acc[h * 4 + 1] += rf * ux;
      acc[h * 4 + 2] += rf * uy;
      acc[h * 4 + 3] += rf * uz;
    }
  }

  {
    #pragma unroll
    for (int i = 0; i < 32; ++i) accT[tid * 33 + i] = acc[i];
    __syncthreads();
    {
      const int j2 = tid & 31, q2 = tid >> 5;
      float a0 = 0.f, a1 = 0.f;
      #pragma unroll 8
      for (int rr = 0; rr < 32; rr += 2) {
        a0 += accT[(q2 * 32 + rr) * 33 + j2];
        a1 += accT[(q2 * 32 + rr + 1) * 33 + j2];
      }
      red8[q2][j2] = a0 + a1;
    }
    __syncthreads();
    if (tid < 32) {
      float a = 0.f;
      #pragma unroll
      for (int g = 0; g < 8; ++g) a += red8[g][tid];
      fin[tid] = a;
    }
    __syncthreads();

    #pragma unroll
    for (int i = 0; i < 32; ++i) accT[tid * 33 + i] = acc[32 + i];
    __syncthreads();
    {
      const int j2 = tid & 31, q2 = tid >> 5;
      float a0 = 0.f, a1 = 0.f;
      #pragma unroll 8
      for (int rr = 0; rr < 32; rr += 2) {
        a0 += accT[(q2 * 32 + rr) * 33 + j2];
        a1 += accT[(q2 * 32 + rr + 1) * 33 + j2];
      }
      red8[q2][j2] = a0 + a1;
    }
    __syncthreads();
    if (tid < 32) {
      float a = 0.f;
      #pragma unroll
      for (int g = 0; g < 8; ++g) a += red8[g][tid];
      fin[32 + tid] = a;
    }
    __syncthreads();
  }

  if (tid < FF) {
    float a = 0.f;
    #pragma unroll
    for (int hh = 0; hh < RH; ++hh) a += fin[hh * 4] * Wr2s[hh * FF + tid];
    as_l[tid] = a * embed[tid] * (1.0f / 64.0f);
  }
  if (tid < 192) {
    const int v = tid / 3, d = tid - v * 3;
    float a = 0.f;
    #pragma unroll
    for (int hh = 0; hh < RH; ++hh) a += fin[hh * 4 + 1 + d] * Wr2v[hh * VV + v];
    av_l[tid] = a * cvs[v] * (1.0f / 64.0f);
  }
  __syncthreads();

  if (tid < VV) {
    const float a0 = av_l[tid * 3 + 0], a1 = av_l[tid * 3 + 1], a2 = av_l[tid * 3 + 2];
    inv_l[tid] = a0 * a0 + a1 * a1 + a2 * a2;
  }
  __syncthreads();

  {
    const int f = tid & 127, part = tid >> 7;
    float a = 0.f;
    const float* wp = Wss + (part * 64) * FF + f;
    #pragma unroll 8
    for (int kk = 0; kk < 64; ++kk) a += as_l[part * 64 + kk] * wp[kk * FF];
    const float* vp = Wvs + (part * 32) * FF + f;
    #pragma unroll 8
    for (int vv = 0; vv < 32; ++vv) a += inv_l[part * 32 + vv] * vp[vv * FF];
    redn[part * 128 + f] = a;
  }
  __syncthreads();

  if (tid < FF) {
    const float hnew = silu_f(embed[tid] + redn[tid] + redn[128 + tid]);
    hs[(size_t)r * FF + tid] = hnew;
    hsn[tid] = hnew;
  }
  if (tid < 192) {
    const int w = tid / 3, d = tid - w * 3;
    float a = 0.f;
    #pragma unroll 8
    for (int v = 0; v < VV; ++v) a += av_l[v * 3 + d] * Wvv[v * VV + w];
    hv[(size_t)r * 192 + tid] = a;
  }
  __syncthreads();

  {
    const int v = tid & 63, part = tid >> 6;
    float a = 0.f;
    const float* wp = Wsv1 + (part * 32) * VV + v;
    #pragma unroll 8
    for (int f = 0; f < 32; ++f) a += hsn[part * 32 + f] * wp[f * VV];
    redn[tid] = a;
  }
  __syncthreads();
  if (tid < VV)
    hsv_l[tid] = redn[tid] + redn[64 + tid] + redn[128 + tid] + redn[192 + tid];
  __syncthreads();

  // ---- fused B emission for layer 1 ----
  {
    const float* W2s = Wr2s + RH * FF;
    const float* W2v = Wr2v + RH * VV;
    const int s     = r;
    const int kstep = s >> 1;
    const int lbase = (s & 1) << 5;
    const float xs0 = x[s * 3 + 0], xs1 = x[s * 3 + 1], xs2 = x[s * 3 + 2];

    #pragma unroll
    for (int k = 0; k < 3; ++k) {
      const int item  = tid + k * 256;
      const int ntile = item >> 5;
      const int li    = item & 31;
      const int lane  = lbase + li;
      const int hb    = ((li >> 4) & 1) * 8;

      bf16x8_t o;
      if (ntile < NT_S) {
        const int f = ntile * 16 + (li & 15);
        const float hf = hsn[f] * 0.015625f;
        #pragma unroll
        for (int e = 0; e < 8; ++e)
          o[e] = f2bf(hf * W2s[(hb + e) * FF + f]);
        *(bf16x8_t*)&Bs[((size_t)(kstep * NT_S + ntile) * 64 + lane) * 8] = o;
      } else {
        const int nt2 = ntile - NT_S;
        const int n   = nt2 * 16 + (li & 15);
        int v; float scale;
        if (n < 192) {
          const int dd = n >> 6; v = n & 63;
          const float xd = (dd == 0) ? xs0 : ((dd == 1) ? xs1 : xs2);
          scale = xd * hsv_l[v] * 0.015625f;
        } else {
          v = n - 192; scale = hsv_l[v] * 0.015625f;
        }
        #pragma unroll
        for (int e = 0; e < 8; ++e)
          o[e] = f2bf(scale * W2v[(hb + e) * VV + v]);
        *(bf16x8_t*)&Bv[((size_t)(kstep * NT_V + nt2) * 64 + lane) * 8] = o;
      }
    }
  }
}

// ---------------------------------------------------------------------------
// edge GEMM (R15-phase3 verbatim, standalone): SPLITK=32, grid = 24x32 = 768
// = exactly 3 blocks/CU. M=32/block, combined kinds, bf16 partial output.
// ---------------------------------------------------------------------------
__global__ __launch_bounds__(256) void edge_gemm(
    const float* __restrict__ x,
    const unsigned short* __restrict__ Bs,
    const unsigned short* __restrict__ Bv,
    const float* __restrict__ Wr1,    // [16] layer-1 slice
    unsigned short* __restrict__ Ps,  // [SPLITK][768][128] bf16
    unsigned short* __restrict__ Pv)  // [SPLITK][768][256] bf16
{
  __shared__ unsigned short A_lds[4 * 2 * 64 * 8];  // 8 KB
  __shared__ unsigned short G_lds[4 * 2 * 64 * 8];  // 8 KB

  // bijective XCD swizzle: 768 = 8 * 96; xcd owns kc in [4*xcd, 4*xcd+4)
  const int wg = ((blockIdx.x & 7) * 96) + (blockIdx.x >> 3);
  const int kc = wg / MB_N;        // 0..31
  const int mb = wg - kc * MB_N;   // 0..23

  const int tid  = threadIdx.x;
  const int lane = tid & 63;
  const int w    = tid >> 6;

  float wr1[RH];
  #pragma unroll
  for (int h = 0; h < RH; ++h) wr1[h] = Wr1[h];

  const int r_local = tid & 31;
  const int s_ii    = tid >> 5;
  const int r = mb * 32 + r_local;
  const int mt_w  = r_local >> 4;
  const int ks_w  = s_ii >> 1;
  const int lane0 = (r_local & 15) + ((s_ii & 1) << 5);

  const float xr0 = x[r * 3 + 0], xr1 = x[r * 3 + 1], xr2 = x[r * 3 + 2];
  float sx[NITER], sy[NITER], sz[NITER];
  #pragma unroll
  for (int it = 0; it < NITER; ++it) {
    const int s = kc * SEND_PER_KC + it * 8 + s_ii;
    sx[it] = x[s * 3 + 0]; sy[it] = x[s * 3 + 1]; sz[it] = x[s * 3 + 2];
  }

  f32x4 accS[4], accV[8];
  #pragma unroll
  for (int i = 0; i < 4; ++i) accS[i] = (f32x4){0.f, 0.f, 0.f, 0.f};
  #pragma unroll
  for (int i = 0; i < 8; ++i) accV[i] = (f32x4){0.f, 0.f, 0.f, 0.f};

  for (int it = 0; it < NITER; ++it) {
    {
      const float vx = sx[it] - xr0;
      const float vy = sy[it] - xr1;
      const float vz = sz[it] - xr2;
      const float dd = __builtin_amdgcn_sqrtf(vx * vx + vy * vy + vz * vz);
      const float iv = __builtin_amdgcn_rcpf(dd + 1e-8f);
      float sv[RH];
      #pragma unroll
      for (int h = 0; h < RH; ++h) sv[h] = silu_f(dd * wr1[h]);
      bf16x8_t o0, o1, g0, g1;
      #pragma unroll
      for (int h = 0; h < 8; ++h) {
        o0[h] = f2bf(sv[h]);
        o1[h] = f2bf(sv[h + 8]);
        g0[h] = f2bf(sv[h] * iv);
        g1[h] = f2bf(sv[h + 8] * iv);
      }
      const int off0 = ((ks_w * 2 + mt_w) * 64 + lane0) * 8;
      *(bf16x8_t*)&A_lds[off0]       = o0;
      *(bf16x8_t*)&A_lds[off0 + 128] = o1;
      *(bf16x8_t*)&G_lds[off0]       = g0;
      *(bf16x8_t*)&G_lds[off0 + 128] = g1;
    }
    __syncthreads();

    const int kgb = kc * (SEND_PER_KC / 2) + it * 4;
    #pragma unroll
    for (int ks = 0; ks < 4; ++ks) {
      const bf16x8_t b0 =
          *(const bf16x8_t*)&Bs[((size_t)((kgb + ks) * NT_S + 2 * w) * 64 + lane) * 8];
      const bf16x8_t b1 =
          *(const bf16x8_t*)&Bs[((size_t)((kgb + ks) * NT_S + 2 * w + 1) * 64 + lane) * 8];
      bf16x8_t bv[4];
      #pragma unroll
      for (int j = 0; j < 4; ++j)
        bv[j] = *(const bf16x8_t*)&Bv[((size_t)((kgb + ks) * NT_V + 4 * w + j) * 64 + lane) * 8];
      #pragma unroll
      for (int mt = 0; mt < 2; ++mt) {
        const int aoff = ((ks * 2 + mt) * 64 + lane) * 8;
        const bf16x8_t a  = *(const bf16x8_t*)&A_lds[aoff];
        const bf16x8_t ag = *(const bf16x8_t*)&G_lds[aoff];
        accS[mt * 2 + 0] = __builtin_amdgcn_mfma_f32_16x16x32_bf16(a, b0, accS[mt * 2 + 0], 0, 0, 0);
        accS[mt * 2 + 1] = __builtin_amdgcn_mfma_f32_16x16x32_bf16(a, b1, accS[mt * 2 + 1], 0, 0, 0);
        #pragma unroll
        for (int j = 0; j < 4; ++j)
          accV[mt * 4 + j] = __builtin_amdgcn_mfma_f32_16x16x32_bf16(ag, bv[j], accV[mt * 4 + j], 0, 0, 0);
      }
    }
    __syncthreads();
  }

  const int rowq = (lane >> 4) << 2;
  #pragma unroll
  for (int j = 0; j < 2; ++j) {
    const int col = (2 * w + j) * 16 + (lane & 15);
    #pragma unroll
    for (int mt = 0; mt < 2; ++mt) {
      #pragma unroll
      for (int reg = 0; reg < 4; ++reg) {
        const int row = mb * 32 + mt * 16 + rowq + reg;
        Ps[((size_t)kc * NN + row) * FF + col] =
            (unsigned short)f2bf(accS[mt * 2 + j][reg]);
      }
    }
  }
  #pragma unroll
  for (int j = 0; j < 4; ++j) {
    const int col = (4 * w + j) * 16 + (lane & 15);
    #pragma unroll
    for (int mt = 0; mt < 2; ++mt) {
      #pragma unroll
      for (int reg = 0; reg < 4; ++reg) {
        const int row = mb * 32 + mt * 16 + rowq + reg;
        Pv[((size_t)kc * NN + row) * 256 + col] =
            (unsigned short)f2bf(accV[mt * 4 + j][reg]);
      }
    }
  }
}

// ---------------------------------------------------------------------------
// final kernel v2: 4 NODES PER BLOCK (weights loaded once, applied to 4
// nodes -> 4x less weight traffic). grid = 192 x 512. Same verified math.
// ---------------------------------------------------------------------------
__global__ __launch_bounds__(512) void final_kernel(
    const unsigned short* __restrict__ Ps,  // [SPLITK][768][128] bf16
    const unsigned short* __restrict__ Pv,  // [SPLITK][768][256] bf16
    const float* __restrict__ x,
    const float* __restrict__ hs,       // layer-0 output
    const float* __restrict__ hv,       // layer-0 output
    const float* __restrict__ Wss,      // layer-1
    const float* __restrict__ Wvs,      // layer-1
    const float* __restrict__ Wvv,      // layer-1
    const float* __restrict__ Wro_s1,
    const float* __restrict__ Wro_s2,
    const float* __restrict__ Wro_v1,
    const float* __restrict__ Wro_v2,
    float* __restrict__ out)
{
  __shared__ float as_l[4][FF];
  __shared__ float pvs_l[4][256];
  __shared__ float av_l[4][192];
  __shared__ float inv_l[4][VV];
  __shared__ float hsn[4][FF];
  __shared__ float hv_l[4][192];
  __shared__ float red[4][512];
  __shared__ float t1[4][FF];
  __shared__ float tv1[4][192];
  const int n0 = blockIdx.x * 4;
  const int t  = threadIdx.x;

  // partial reduce: Ps 512 items (1/thread), Pv 1024 items (2/thread)
  {
    const int g = t >> 7, c = t & 127;
    float a = 0.f;
    #pragma unroll
    for (int kc = 0; kc < SPLITK; ++kc)
      a += bf2f(Ps[((size_t)kc * NN + n0 + g) * FF + c]);
    as_l[g][c] = a;
  }
  #pragma unroll
  for (int i = 0; i < 2; ++i) {
    const int item = t + i * 512;
    const int g = item >> 8, c = item & 255;
    float a = 0.f;
    #pragma unroll
    for (int kc = 0; kc < SPLITK; ++kc)
      a += bf2f(Pv[((size_t)kc * NN + n0 + g) * 256 + c]);
    pvs_l[g][c] = a;
  }
  __syncthreads();

  if (t < 256) {
    const int g = t >> 6, v = t & 63;
    const float base = pvs_l[g][192 + v];
    const float a0 = pvs_l[g][v]       - x[(n0 + g) * 3 + 0] * base;
    const float a1 = pvs_l[g][64 + v]  - x[(n0 + g) * 3 + 1] * base;
    const float a2 = pvs_l[g][128 + v] - x[(n0 + g) * 3 + 2] * base;
    av_l[g][v * 3 + 0] = a0; av_l[g][v * 3 + 1] = a1; av_l[g][v * 3 + 2] = a2;
    inv_l[g][v] = a0 * a0 + a1 * a1 + a2 * a2;
  }
  __syncthreads();

  // hs GEMV: 4-way K split, each weight feeds 4 nodes
  {
    const int f = t & 127, part = t >> 7;
    float a0 = 0.f, a1 = 0.f, a2 = 0.f, a3 = 0.f;
    const float* wp = Wss + (part * 32) * FF + f;
    #pragma unroll 4
    for (int kk = 0; kk < 32; ++kk) {
      const float w = wp[kk * FF];
      const int k = part * 32 + kk;
      a0 += as_l[0][k] * w; a1 += as_l[1][k] * w;
      a2 += as_l[2][k] * w; a3 += as_l[3][k] * w;
    }
    const float* vp = Wvs + (part * 16) * FF + f;
    #pragma unroll 4
    for (int vv = 0; vv < 16; ++vv) {
      const float w = vp[vv * FF];
      const int k = part * 16 + vv;
      a0 += inv_l[0][k] * w; a1 += inv_l[1][k] * w;
      a2 += inv_l[2][k] * w; a3 += inv_l[3][k] * w;
    }
    const int o = part * 128 + f;
    red[0][o] = a0; red[1][o] = a1; red[2][o] = a2; red[3][o] = a3;
  }
  __syncthreads();

  {
    const int g = t >> 7, f = t & 127;
    hsn[g][f] = silu_f(hs[(size_t)(n0 + g) * FF + f] +
                       red[g][f] + red[g][128 + f] + red[g][256 + f] + red[g][384 + f]);
  }
  if (t < 192) {
    const int w = t / 3, d = t - w * 3;
    float a0 = 0.f, a1 = 0.f, a2 = 0.f, a3 = 0.f;
    #pragma unroll 4
    for (int v = 0; v < VV; ++v) {
      const float wv_ = Wvv[v * VV + w];
      a0 += av_l[0][v * 3 + d] * wv_; a1 += av_l[1][v * 3 + d] * wv_;
      a2 += av_l[2][v * 3 + d] * wv_; a3 += av_l[3][v * 3 + d] * wv_;
    }
    hv_l[0][t] = hv[(size_t)(n0 + 0) * 192 + t] + a0;
    hv_l[1][t] = hv[(size_t)(n0 + 1) * 192 + t] + a1;
    hv_l[2][t] = hv[(size_t)(n0 + 2) * 192 + t] + a2;
    hv_l[3][t] = hv[(size_t)(n0 + 3) * 192 + t] + a3;
  }
  __syncthreads();

  // readout t1 GEMV
  {
    const int f = t & 127, part = t >> 7;
    float a0 = 0.f, a1 = 0.f, a2 = 0.f, a3 = 0.f;
    const float* wp = Wro_s1 + (part * 32) * FF + f;
    #pragma unroll 4
    for (int kk = 0; kk < 32; ++kk) {
      const float w = wp[kk * FF];
      const int k = part * 32 + kk;
      a0 += hsn[0][k] * w; a1 += hsn[1][k] * w;
      a2 += hsn[2][k] * w; a3 += hsn[3][k] * w;
    }
    const int o = part * 128 + f;
    red[0][o] = a0; red[1][o] = a1; red[2][o] = a2; red[3][o] = a3;
  }
  __syncthreads();
  {
    const int g = t >> 7, f = t & 127;
    t1[g][f] = silu_f(red[g][f] + red[g][128 + f] + red[g][256 + f] + red[g][384 + f]);
  }
  if (t < 192) {
    const int w = t / 3, d = t - w * 3;
    float a0 = 0.f, a1 = 0.f, a2 = 0.f, a3 = 0.f;
    #pragma unroll 4
    for (int v = 0; v < VV; ++v) {
      const float wv_ = Wro_v1[v * VV + w];
      a0 += hv_l[0][v * 3 + d] * wv_; a1 += hv_l[1][v * 3 + d] * wv_;
      a2 += hv_l[2][v * 3 + d] * wv_; a3 += hv_l[3][v * 3 + d] * wv_;
    }
    tv1[0][t] = a0; tv1[1][t] = a1; tv1[2][t] = a2; tv1[3][t] = a3;
  }
  __syncthreads();

  // out_s partials (4-way K split) || out_v direct
  if (t < 256) {
    const int o = t & 63, part = t >> 6;
    float a0 = 0.f, a1 = 0.f, a2 = 0.f, a3 = 0.f;
    const float* wp = Wro_s2 + (part * 32) * 64 + o;
    #pragma unroll 4
    for (int f2 = 0; f2 < 32; ++f2) {
      const float w = wp[f2 * 64];
      const int k = part * 32 + f2;
      a0 += t1[0][k] * w; a1 += t1[1][k] * w;
      a2 += t1[2][k] * w; a3 += t1[3][k] * w;
    }
    const int oo = part * 64 + o;
    red[0][oo] = a0; red[1][oo] = a1; red[2][oo] = a2; red[3][oo] = a3;
  }
  if (t >= 256 && t < 352) {
    const int j = t - 256;            // 0..95
    const int w2 = j / 3, d = j - w2 * 3;
    float a0 = 0.f, a1 = 0.f, a2 = 0.f, a3 = 0.f;
    #pragma unroll 4
    for (int wv = 0; wv < VV; ++wv) {
      const float w = Wro_v2[wv * 32 + w2];
      a0 += tv1[0][wv * 3 + d] * w; a1 += tv1[1][wv * 3 + d] * w;
      a2 += tv1[2][wv * 3 + d] * w; a3 += tv1[3][wv * 3 + d] * w;
    }
    out[(size_t)(n0 + 0) * 160 + 64 + j] = a0;
    out[(size_t)(n0 + 1) * 160 + 64 + j] = a1;
    out[(size_t)(n0 + 2) * 160 + 64 + j] = a2;
    out[(size_t)(n0 + 3) * 160 + 64 + j] = a3;
  }
  __syncthreads();
  if (t < 256) {
    const int g = t >> 6, o = t & 63;
    out[(size_t)(n0 + g) * 160 + o] =
        red[g][o] + red[g][64 + o] + red[g][128 + o] + red[g][192 + o];
  }
}

// ---------------------------------------------------------------------------
extern "C" void kernel_launch(void* const* d_in, const int* in_sizes, int n_in,
                              void* d_out, int out_size, void* d_ws, size_t ws_size,
                              hipStream_t stream) {
  const float* x      = (const float*)d_in[0];
  const float* embed  = (const float*)d_in[3];
  const float* Wr1    = (const float*)d_in[4];   // [2][1][16]
  const float* Wr2s   = (const float*)d_in[5];   // [2][16][128]
  const float* Wr2v   = (const float*)d_in[6];   // [2][16][64]
  const float* Wsv    = (const float*)d_in[7];   // [2][128][64]
  const float* Wss    = (const float*)d_in[8];   // [2][128][128]
  const float* Wvs    = (const float*)d_in[9];   // [2][64][128]
  const float* Wvv    = (const float*)d_in[10];  // [2][64][64]
  const float* Wro_s1 = (const float*)d_in[11];
  const float* Wro_s2 = (const float*)d_in[12];
  const float* Wro_v1 = (const float*)d_in[13];
  const float* Wro_v2 = (const float*)d_in[14];

  float* ws_f = (float*)d_ws;
  float* hs    = ws_f;                      // 768*128 f32
  float* hv    = hs + NN * FF;              // 768*192 f32
  unsigned short* Ps = (unsigned short*)(hv + NN * 192);       // 32*768*128 bf16
  unsigned short* Pv = Ps + (size_t)SPLITK * NN * FF;          // 32*768*256 bf16
  unsigned short* Bs = Pv + (size_t)SPLITK * NN * 256;         // 12288*128 bf16
  unsigned short* Bv = Bs + (size_t)12288 * 128;               // 12288*256 bf16
  float* out = (float*)d_out;

  // layer 0 (closed form, register moments) + node0 + B emission, fused
  layer0_kernel<<<NN, 256, 0, stream>>>(
      x, Wr1, Wr2s, Wr2v, embed, Wsv, Wss, Wvs, Wvv, Wsv + FF * VV,
      hs, hv, Bs, Bv);

  // layer 1: combined-kind MFMA edge GEMM (3 blocks/CU) -> final (4n/block)
  edge_gemm<<<MB_N * SPLITK, 256, 0, stream>>>(
      x, Bs, Bv, Wr1 + RH, Ps, Pv);
  final_kernel<<<NN / 4, 512, 0, stream>>>(
      Ps, Pv, x, hs, hv, Wss + FF * FF, Wvs + VV * FF, Wvv + VV * VV,
      Wro_s1, Wro_s2, Wro_v1, Wro_v2, out);
}

// Round 19
// 58.199 us; speedup vs baseline: 1.1064x; 1.1064x over previous
//
#include <hip/hip_runtime.h>
#include <hip/hip_bf16.h>
#include <math.h>

#define NN 768
#define FF 128
#define VV 64
#define RH 16
#define SPLITK 32
#define SEND_PER_KC 24          // 768 / SPLITK
#define NITER 3                 // SEND_PER_KC / 8 senders per iter
#define KSTEPS 384              // 12288 / 32
#define NT_S 8                  // scalar n-tiles (128/16)
#define NT_V 16                 // vector n-tiles (256/16)
#define MB_N 24                 // M-blocks (768/32)

typedef __attribute__((ext_vector_type(8))) short bf16x8_t;
typedef __attribute__((ext_vector_type(4))) float f32x4;

__device__ __forceinline__ float silu_f(float a) {
  return a * __builtin_amdgcn_rcpf(1.0f + __expf(-a));
}

__device__ __forceinline__ short f2bf(float f) {
  __hip_bfloat16 h = __float2bfloat16(f);  // RNE; pairs into v_cvt_pk_bf16_f32
  return __builtin_bit_cast(short, h);
}

__device__ __forceinline__ float bf2f(unsigned short v) {
  return __builtin_bit_cast(float, (unsigned)v << 16);
}

// ---------------------------------------------------------------------------
// Layer-0 fused kernel (R17 verbatim): register-resident moments + node
// update + direct B-fragment emission for layer 1.
// ---------------------------------------------------------------------------
__global__ __launch_bounds__(256) void layer0_kernel(
    const float* __restrict__ x,
    const float* __restrict__ Wr1,    // [16] layer-0
    const float* __restrict__ Wr2s,   // [2][16][128] (both layers)
    const float* __restrict__ Wr2v,   // [2][16][64]
    const float* __restrict__ embed,  // [128]
    const float* __restrict__ Wsv0,   // [128][64] layer-0
    const float* __restrict__ Wss,    // [128][128] layer-0
    const float* __restrict__ Wvs,    // [64][128]  layer-0
    const float* __restrict__ Wvv,    // [64][64]   layer-0
    const float* __restrict__ Wsv1,   // [128][64]  layer-1 (for hsv)
    float* __restrict__ hs,
    float* __restrict__ hv,
    unsigned short* __restrict__ Bs,  // [384*8][64][8] bf16
    unsigned short* __restrict__ Bv)  // [384*16][64][8] bf16
{
  __shared__ float accT[256 * 33];
  __shared__ float red8[8][32];
  __shared__ float fin[64];
  __shared__ float cvs[64];
  __shared__ float as_l[FF];
  __shared__ float av_l[192];
  __shared__ float inv_l[VV];
  __shared__ float hsn[FF];
  __shared__ float hsv_l[VV];
  __shared__ float redn[256];

  const int r   = blockIdx.x;
  const int tid = threadIdx.x;

  if (tid < 64) {
    float a = 0.f;
    #pragma unroll 8
    for (int f = 0; f < FF; ++f) a += embed[f] * Wsv0[f * VV + tid];
    cvs[tid] = a;
  }

  float wr1[RH];
  #pragma unroll
  for (int hh = 0; hh < RH; ++hh) wr1[hh] = Wr1[hh];

  const float xr0 = x[r * 3 + 0], xr1 = x[r * 3 + 1], xr2 = x[r * 3 + 2];

  float acc[64];
  #pragma unroll
  for (int i = 0; i < 64; ++i) acc[i] = 0.f;

  #pragma unroll
  for (int ss = 0; ss < 3; ++ss) {
    const int s = tid + ss * 256;
    const float vx = x[s * 3 + 0] - xr0;
    const float vy = x[s * 3 + 1] - xr1;
    const float vz = x[s * 3 + 2] - xr2;
    const float d  = __builtin_amdgcn_sqrtf(vx * vx + vy * vy + vz * vz);
    const float iv = __builtin_amdgcn_rcpf(d + 1e-8f);
    const float ux = vx * iv, uy = vy * iv, uz = vz * iv;
    #pragma unroll
    for (int h = 0; h < RH; ++h) {
      const float rf = silu_f(d * wr1[h]);
      acc[h * 4 + 0] += rf;
      acc[h * 4 + 1] += rf * ux;
      acc[h * 4 + 2] += rf * uy;
      acc[h * 4 + 3] += rf * uz;
    }
  }

  {
    #pragma unroll
    for (int i = 0; i < 32; ++i) accT[tid * 33 + i] = acc[i];
    __syncthreads();
    {
      const int j2 = tid & 31, q2 = tid >> 5;
      float a0 = 0.f, a1 = 0.f;
      #pragma unroll 8
      for (int rr = 0; rr < 32; rr += 2) {
        a0 += accT[(q2 * 32 + rr) * 33 + j2];
        a1 += accT[(q2 * 32 + rr + 1) * 33 + j2];
      }
      red8[q2][j2] = a0 + a1;
    }
    __syncthreads();
    if (tid < 32) {
      float a = 0.f;
      #pragma unroll
      for (int g = 0; g < 8; ++g) a += red8[g][tid];
      fin[tid] = a;
    }
    __syncthreads();

    #pragma unroll
    for (int i = 0; i < 32; ++i) accT[tid * 33 + i] = acc[32 + i];
    __syncthreads();
    {
      const int j2 = tid & 31, q2 = tid >> 5;
      float a0 = 0.f, a1 = 0.f;
      #pragma unroll 8
      for (int rr = 0; rr < 32; rr += 2) {
        a0 += accT[(q2 * 32 + rr) * 33 + j2];
        a1 += accT[(q2 * 32 + rr + 1) * 33 + j2];
      }
      red8[q2][j2] = a0 + a1;
    }
    __syncthreads();
    if (tid < 32) {
      float a = 0.f;
      #pragma unroll
      for (int g = 0; g < 8; ++g) a += red8[g][tid];
      fin[32 + tid] = a;
    }
    __syncthreads();
  }

  if (tid < FF) {
    float a = 0.f;
    #pragma unroll
    for (int hh = 0; hh < RH; ++hh) a += fin[hh * 4] * Wr2s[hh * FF + tid];
    as_l[tid] = a * embed[tid] * (1.0f / 64.0f);
  }
  if (tid < 192) {
    const int v = tid / 3, d = tid - v * 3;
    float a = 0.f;
    #pragma unroll
    for (int hh = 0; hh < RH; ++hh) a += fin[hh * 4 + 1 + d] * Wr2v[hh * VV + v];
    av_l[tid] = a * cvs[v] * (1.0f / 64.0f);
  }
  __syncthreads();

  if (tid < VV) {
    const float a0 = av_l[tid * 3 + 0], a1 = av_l[tid * 3 + 1], a2 = av_l[tid * 3 + 2];
    inv_l[tid] = a0 * a0 + a1 * a1 + a2 * a2;
  }
  __syncthreads();

  {
    const int f = tid & 127, part = tid >> 7;
    float a = 0.f;
    const float* wp = Wss + (part * 64) * FF + f;
    #pragma unroll 8
    for (int kk = 0; kk < 64; ++kk) a += as_l[part * 64 + kk] * wp[kk * FF];
    const float* vp = Wvs + (part * 32) * FF + f;
    #pragma unroll 8
    for (int vv = 0; vv < 32; ++vv) a += inv_l[part * 32 + vv] * vp[vv * FF];
    redn[part * 128 + f] = a;
  }
  __syncthreads();

  if (tid < FF) {
    const float hnew = silu_f(embed[tid] + redn[tid] + redn[128 + tid]);
    hs[(size_t)r * FF + tid] = hnew;
    hsn[tid] = hnew;
  }
  if (tid < 192) {
    const int w = tid / 3, d = tid - w * 3;
    float a = 0.f;
    #pragma unroll 8
    for (int v = 0; v < VV; ++v) a += av_l[v * 3 + d] * Wvv[v * VV + w];
    hv[(size_t)r * 192 + tid] = a;
  }
  __syncthreads();

  {
    const int v = tid & 63, part = tid >> 6;
    float a = 0.f;
    const float* wp = Wsv1 + (part * 32) * VV + v;
    #pragma unroll 8
    for (int f = 0; f < 32; ++f) a += hsn[part * 32 + f] * wp[f * VV];
    redn[tid] = a;
  }
  __syncthreads();
  if (tid < VV)
    hsv_l[tid] = redn[tid] + redn[64 + tid] + redn[128 + tid] + redn[192 + tid];
  __syncthreads();

  // ---- fused B emission for layer 1 ----
  {
    const float* W2s = Wr2s + RH * FF;
    const float* W2v = Wr2v + RH * VV;
    const int s     = r;
    const int kstep = s >> 1;
    const int lbase = (s & 1) << 5;
    const float xs0 = x[s * 3 + 0], xs1 = x[s * 3 + 1], xs2 = x[s * 3 + 2];

    #pragma unroll
    for (int k = 0; k < 3; ++k) {
      const int item  = tid + k * 256;
      const int ntile = item >> 5;
      const int li    = item & 31;
      const int lane  = lbase + li;
      const int hb    = ((li >> 4) & 1) * 8;

      bf16x8_t o;
      if (ntile < NT_S) {
        const int f = ntile * 16 + (li & 15);
        const float hf = hsn[f] * 0.015625f;
        #pragma unroll
        for (int e = 0; e < 8; ++e)
          o[e] = f2bf(hf * W2s[(hb + e) * FF + f]);
        *(bf16x8_t*)&Bs[((size_t)(kstep * NT_S + ntile) * 64 + lane) * 8] = o;
      } else {
        const int nt2 = ntile - NT_S;
        const int n   = nt2 * 16 + (li & 15);
        int v; float scale;
        if (n < 192) {
          const int dd = n >> 6; v = n & 63;
          const float xd = (dd == 0) ? xs0 : ((dd == 1) ? xs1 : xs2);
          scale = xd * hsv_l[v] * 0.015625f;
        } else {
          v = n - 192; scale = hsv_l[v] * 0.015625f;
        }
        #pragma unroll
        for (int e = 0; e < 8; ++e)
          o[e] = f2bf(scale * W2v[(hb + e) * VV + v]);
        *(bf16x8_t*)&Bv[((size_t)(kstep * NT_V + nt2) * 64 + lane) * 8] = o;
      }
    }
  }
}

// ---------------------------------------------------------------------------
// edge GEMM (R18 edge, verified): SPLITK=32, grid = 24x32 = 768 = exactly
// 3 blocks/CU (uniform, no imbalance tail). M=32/block, combined kinds.
// ---------------------------------------------------------------------------
__global__ __launch_bounds__(256) void edge_gemm(
    const float* __restrict__ x,
    const unsigned short* __restrict__ Bs,
    const unsigned short* __restrict__ Bv,
    const float* __restrict__ Wr1,    // [16] layer-1 slice
    unsigned short* __restrict__ Ps,  // [SPLITK][768][128] bf16
    unsigned short* __restrict__ Pv)  // [SPLITK][768][256] bf16
{
  __shared__ unsigned short A_lds[4 * 2 * 64 * 8];  // 8 KB
  __shared__ unsigned short G_lds[4 * 2 * 64 * 8];  // 8 KB

  // bijective XCD swizzle: 768 = 8 * 96; xcd owns kc in [4*xcd, 4*xcd+4)
  const int wg = ((blockIdx.x & 7) * 96) + (blockIdx.x >> 3);
  const int kc = wg / MB_N;        // 0..31
  const int mb = wg - kc * MB_N;   // 0..23

  const int tid  = threadIdx.x;
  const int lane = tid & 63;
  const int w    = tid >> 6;

  float wr1[RH];
  #pragma unroll
  for (int h = 0; h < RH; ++h) wr1[h] = Wr1[h];

  const int r_local = tid & 31;
  const int s_ii    = tid >> 5;
  const int r = mb * 32 + r_local;
  const int mt_w  = r_local >> 4;
  const int ks_w  = s_ii >> 1;
  const int lane0 = (r_local & 15) + ((s_ii & 1) << 5);

  const float xr0 = x[r * 3 + 0], xr1 = x[r * 3 + 1], xr2 = x[r * 3 + 2];
  float sx[NITER], sy[NITER], sz[NITER];
  #pragma unroll
  for (int it = 0; it < NITER; ++it) {
    const int s = kc * SEND_PER_KC + it * 8 + s_ii;
    sx[it] = x[s * 3 + 0]; sy[it] = x[s * 3 + 1]; sz[it] = x[s * 3 + 2];
  }

  f32x4 accS[4], accV[8];
  #pragma unroll
  for (int i = 0; i < 4; ++i) accS[i] = (f32x4){0.f, 0.f, 0.f, 0.f};
  #pragma unroll
  for (int i = 0; i < 8; ++i) accV[i] = (f32x4){0.f, 0.f, 0.f, 0.f};

  for (int it = 0; it < NITER; ++it) {
    {
      const float vx = sx[it] - xr0;
      const float vy = sy[it] - xr1;
      const float vz = sz[it] - xr2;
      const float dd = __builtin_amdgcn_sqrtf(vx * vx + vy * vy + vz * vz);
      const float iv = __builtin_amdgcn_rcpf(dd + 1e-8f);
      float sv[RH];
      #pragma unroll
      for (int h = 0; h < RH; ++h) sv[h] = silu_f(dd * wr1[h]);
      bf16x8_t o0, o1, g0, g1;
      #pragma unroll
      for (int h = 0; h < 8; ++h) {
        o0[h] = f2bf(sv[h]);
        o1[h] = f2bf(sv[h + 8]);
        g0[h] = f2bf(sv[h] * iv);
        g1[h] = f2bf(sv[h + 8] * iv);
      }
      const int off0 = ((ks_w * 2 + mt_w) * 64 + lane0) * 8;
      *(bf16x8_t*)&A_lds[off0]       = o0;
      *(bf16x8_t*)&A_lds[off0 + 128] = o1;
      *(bf16x8_t*)&G_lds[off0]       = g0;
      *(bf16x8_t*)&G_lds[off0 + 128] = g1;
    }
    __syncthreads();

    const int kgb = kc * (SEND_PER_KC / 2) + it * 4;
    #pragma unroll
    for (int ks = 0; ks < 4; ++ks) {
      const bf16x8_t b0 =
          *(const bf16x8_t*)&Bs[((size_t)((kgb + ks) * NT_S + 2 * w) * 64 + lane) * 8];
      const bf16x8_t b1 =
          *(const bf16x8_t*)&Bs[((size_t)((kgb + ks) * NT_S + 2 * w + 1) * 64 + lane) * 8];
      bf16x8_t bv[4];
      #pragma unroll
      for (int j = 0; j < 4; ++j)
        bv[j] = *(const bf16x8_t*)&Bv[((size_t)((kgb + ks) * NT_V + 4 * w + j) * 64 + lane) * 8];
      #pragma unroll
      for (int mt = 0; mt < 2; ++mt) {
        const int aoff = ((ks * 2 + mt) * 64 + lane) * 8;
        const bf16x8_t a  = *(const bf16x8_t*)&A_lds[aoff];
        const bf16x8_t ag = *(const bf16x8_t*)&G_lds[aoff];
        accS[mt * 2 + 0] = __builtin_amdgcn_mfma_f32_16x16x32_bf16(a, b0, accS[mt * 2 + 0], 0, 0, 0);
        accS[mt * 2 + 1] = __builtin_amdgcn_mfma_f32_16x16x32_bf16(a, b1, accS[mt * 2 + 1], 0, 0, 0);
        #pragma unroll
        for (int j = 0; j < 4; ++j)
          accV[mt * 4 + j] = __builtin_amdgcn_mfma_f32_16x16x32_bf16(ag, bv[j], accV[mt * 4 + j], 0, 0, 0);
      }
    }
    __syncthreads();
  }

  const int rowq = (lane >> 4) << 2;
  #pragma unroll
  for (int j = 0; j < 2; ++j) {
    const int col = (2 * w + j) * 16 + (lane & 15);
    #pragma unroll
    for (int mt = 0; mt < 2; ++mt) {
      #pragma unroll
      for (int reg = 0; reg < 4; ++reg) {
        const int row = mb * 32 + mt * 16 + rowq + reg;
        Ps[((size_t)kc * NN + row) * FF + col] =
            (unsigned short)f2bf(accS[mt * 2 + j][reg]);
      }
    }
  }
  #pragma unroll
  for (int j = 0; j < 4; ++j) {
    const int col = (4 * w + j) * 16 + (lane & 15);
    #pragma unroll
    for (int mt = 0; mt < 2; ++mt) {
      #pragma unroll
      for (int reg = 0; reg < 4; ++reg) {
        const int row = mb * 32 + mt * 16 + rowq + reg;
        Pv[((size_t)kc * NN + row) * 256 + col] =
            (unsigned short)f2bf(accV[mt * 4 + j][reg]);
      }
    }
  }
}

// ---------------------------------------------------------------------------
// final kernel (R17 verbatim, SPLITK follows macro): node1 + readout fused,
// 768 blocks (3/CU -> phase latency hidden by neighbor blocks).
// ---------------------------------------------------------------------------
__global__ __launch_bounds__(512) void final_kernel(
    const unsigned short* __restrict__ Ps,  // [SPLITK][768][128] bf16
    const unsigned short* __restrict__ Pv,  // [SPLITK][768][256] bf16
    const float* __restrict__ x,
    const float* __restrict__ hs,       // layer-0 output
    const float* __restrict__ hv,       // layer-0 output
    const float* __restrict__ Wss,      // layer-1
    const float* __restrict__ Wvs,      // layer-1
    const float* __restrict__ Wvv,      // layer-1
    const float* __restrict__ Wro_s1,
    const float* __restrict__ Wro_s2,
    const float* __restrict__ Wro_v1,
    const float* __restrict__ Wro_v2,
    float* __restrict__ out)
{
  __shared__ float as_l[FF];
  __shared__ float pvs_l[256];
  __shared__ float av_l[192];
  __shared__ float inv_l[VV];
  __shared__ float hsn[FF];
  __shared__ float hv_l[192];
  __shared__ float red[512];
  __shared__ float red2[384];
  __shared__ float t1[FF];
  __shared__ float tv1[192];
  const int n = blockIdx.x, t = threadIdx.x;

  // fused splitK reduce (bf16 loads)
  if (t < FF) {
    float a = 0.f;
    #pragma unroll
    for (int kc = 0; kc < SPLITK; ++kc)
      a += bf2f(Ps[((size_t)kc * NN + n) * FF + t]);
    as_l[t] = a;
  } else if (t < 384) {
    const int cc = t - 128;
    float a = 0.f;
    #pragma unroll
    for (int kc = 0; kc < SPLITK; ++kc)
      a += bf2f(Pv[((size_t)kc * NN + n) * 256 + cc]);
    pvs_l[cc] = a;
  }
  __syncthreads();

  if (t < VV) {
    const float base = pvs_l[192 + t];
    const float a0 = pvs_l[t]       - x[n * 3 + 0] * base;
    const float a1 = pvs_l[64 + t]  - x[n * 3 + 1] * base;
    const float a2 = pvs_l[128 + t] - x[n * 3 + 2] * base;
    av_l[t * 3 + 0] = a0; av_l[t * 3 + 1] = a1; av_l[t * 3 + 2] = a2;
    inv_l[t] = a0 * a0 + a1 * a1 + a2 * a2;
  }
  __syncthreads();

  // hs partials: 4-way split over K
  {
    const int f = t & 127, part = t >> 7;
    float acc = 0.f;
    const float* wp = Wss + (part * 32) * FF + f;
    #pragma unroll 8
    for (int kk = 0; kk < 32; ++kk) acc += as_l[part * 32 + kk] * wp[kk * FF];
    const float* vp = Wvs + (part * 16) * FF + f;
    #pragma unroll 8
    for (int vv = 0; vv < 16; ++vv) acc += inv_l[part * 16 + vv] * vp[vv * FF];
    red[part * 128 + f] = acc;
  }
  __syncthreads();

  if (t < FF) {
    hsn[t] = silu_f(hs[n * FF + t] + red[t] + red[128 + t] + red[256 + t] + red[384 + t]);
  }
  if (t < 384) {
    const int part = t / 192, j = t - part * 192;
    const int wv = j / 3, d = j - wv * 3;
    float acc = 0.f;
    const float* vp = Wvv + (part * 32) * VV + wv;
    #pragma unroll 8
    for (int v = 0; v < 32; ++v) acc += av_l[(part * 32 + v) * 3 + d] * vp[v * VV];
    red2[part * 192 + j] = acc;
  }
  __syncthreads();

  if (t < 192) hv_l[t] = hv[n * 192 + t] + red2[t] + red2[192 + t];
  __syncthreads();

  // ---- readout, inputs hsn / hv_l ----
  {
    const int f = t & 127, part = t >> 7;
    float acc = 0.f;
    const float* wp = Wro_s1 + (part * 32) * FF + f;
    #pragma unroll 8
    for (int kk = 0; kk < 32; ++kk) acc += hsn[part * 32 + kk] * wp[kk * FF];
    red[part * 128 + f] = acc;
  }
  __syncthreads();
  if (t < FF) t1[t] = silu_f(red[t] + red[128 + t] + red[256 + t] + red[384 + t]);
  if (t < 384) {
    const int part = t / 192, j = t - part * 192;
    const int wv = j / 3, d = j - wv * 3;
    float acc = 0.f;
    const float* vp = Wro_v1 + (part * 32) * VV + wv;
    #pragma unroll 8
    for (int v = 0; v < 32; ++v) acc += hv_l[(part * 32 + v) * 3 + d] * vp[v * VV];
    red2[part * 192 + j] = acc;
  }
  __syncthreads();
  if (t < 192) tv1[t] = red2[t] + red2[192 + t];
  if (t < 256) {
    const int o = t & 63, part = t >> 6;
    float acc = 0.f;
    const float* wp = Wro_s2 + (part * 32) * 64 + o;
    #pragma unroll 8
    for (int f = 0; f < 32; ++f) acc += t1[part * 32 + f] * wp[f * 64];
    red[t] = acc;
  }
  __syncthreads();
  if (t < 64) out[n * 160 + t] = red[t] + red[64 + t] + red[128 + t] + red[192 + t];
  if (t < 192) {
    const int part = t / 96, j = t - part * 96;
    const int w2 = j / 3, d = j - w2 * 3;
    float acc = 0.f;
    const float* vp = Wro_v2 + (part * 32) * 32 + w2;
    #pragma unroll 8
    for (int wv = 0; wv < 32; ++wv) acc += tv1[(part * 32 + wv) * 3 + d] * vp[wv * 32];
    red2[part * 96 + j] = acc;
  }
  __syncthreads();
  if (t < 96) out[n * 160 + 64 + t] = red2[t] + red2[96 + t];
}

// ---------------------------------------------------------------------------
extern "C" void kernel_launch(void* const* d_in, const int* in_sizes, int n_in,
                              void* d_out, int out_size, void* d_ws, size_t ws_size,
                              hipStream_t stream) {
  const float* x      = (const float*)d_in[0];
  const float* embed  = (const float*)d_in[3];
  const float* Wr1    = (const float*)d_in[4];   // [2][1][16]
  const float* Wr2s   = (const float*)d_in[5];   // [2][16][128]
  const float* Wr2v   = (const float*)d_in[6];   // [2][16][64]
  const float* Wsv    = (const float*)d_in[7];   // [2][128][64]
  const float* Wss    = (const float*)d_in[8];   // [2][128][128]
  const float* Wvs    = (const float*)d_in[9];   // [2][64][128]
  const float* Wvv    = (const float*)d_in[10];  // [2][64][64]
  const float* Wro_s1 = (const float*)d_in[11];
  const float* Wro_s2 = (const float*)d_in[12];
  const float* Wro_v1 = (const float*)d_in[13];
  const float* Wro_v2 = (const float*)d_in[14];

  float* ws_f = (float*)d_ws;
  float* hs    = ws_f;                      // 768*128 f32
  float* hv    = hs + NN * FF;              // 768*192 f32
  unsigned short* Ps = (unsigned short*)(hv + NN * 192);       // 32*768*128 bf16
  unsigned short* Pv = Ps + (size_t)SPLITK * NN * FF;          // 32*768*256 bf16
  unsigned short* Bs = Pv + (size_t)SPLITK * NN * 256;         // 12288*128 bf16
  unsigned short* Bv = Bs + (size_t)12288 * 128;               // 12288*256 bf16
  float* out = (float*)d_out;

  // layer 0 (closed form, register moments) + node0 + B emission, fused
  layer0_kernel<<<NN, 256, 0, stream>>>(
      x, Wr1, Wr2s, Wr2v, embed, Wsv, Wss, Wvs, Wvv, Wsv + FF * VV,
      hs, hv, Bs, Bv);

  // layer 1: combined-kind MFMA edge GEMM (3 blocks/CU uniform) -> final
  edge_gemm<<<MB_N * SPLITK, 256, 0, stream>>>(
      x, Bs, Bv, Wr1 + RH, Ps, Pv);
  final_kernel<<<NN, 512, 0, stream>>>(
      Ps, Pv, x, hs, hv, Wss + FF * FF, Wvs + VV * FF, Wvv + VV * VV,
      Wro_s1, Wro_s2, Wro_v1, Wro_v2, out);
}

// Round 20
// 54.129 us; speedup vs baseline: 1.1896x; 1.0752x over previous
//
#include <hip/hip_runtime.h>
#include <hip/hip_bf16.h>
#include <math.h>

#define NN 768
#define FF 128
#define VV 64
#define RH 16
#define SPLITK 24
#define SEND_PER_KC 32          // 768 / SPLITK
#define NITER 4                 // SEND_PER_KC / 8 senders per iter
#define KSTEPS 384              // 12288 / 32
#define NT_S 8                  // scalar n-tiles (128/16)
#define NT_V 16                 // vector n-tiles (256/16)
#define MB_N 24                 // M-blocks (768/32)

typedef __attribute__((ext_vector_type(8))) short bf16x8_t;
typedef __attribute__((ext_vector_type(4))) float f32x4;

__device__ __forceinline__ float silu_f(float a) {
  return a * __builtin_amdgcn_rcpf(1.0f + __expf(-a));
}

__device__ __forceinline__ short f2bf(float f) {
  __hip_bfloat16 h = __float2bfloat16(f);  // RNE; pairs into v_cvt_pk_bf16_f32
  return __builtin_bit_cast(short, h);
}

__device__ __forceinline__ float bf2f(unsigned short v) {
  return __builtin_bit_cast(float, (unsigned)v << 16);
}

// ---------------------------------------------------------------------------
// Layer-0 fused kernel (R17 verbatim): register-resident moments + node
// update + direct B-fragment emission for layer 1.
// ---------------------------------------------------------------------------
__global__ __launch_bounds__(256) void layer0_kernel(
    const float* __restrict__ x,
    const float* __restrict__ Wr1,    // [16] layer-0
    const float* __restrict__ Wr2s,   // [2][16][128] (both layers)
    const float* __restrict__ Wr2v,   // [2][16][64]
    const float* __restrict__ embed,  // [128]
    const float* __restrict__ Wsv0,   // [128][64] layer-0
    const float* __restrict__ Wss,    // [128][128] layer-0
    const float* __restrict__ Wvs,    // [64][128]  layer-0
    const float* __restrict__ Wvv,    // [64][64]   layer-0
    const float* __restrict__ Wsv1,   // [128][64]  layer-1 (for hsv)
    float* __restrict__ hs,
    float* __restrict__ hv,
    unsigned short* __restrict__ Bs,  // [384*8][64][8] bf16
    unsigned short* __restrict__ Bv)  // [384*16][64][8] bf16
{
  __shared__ float accT[256 * 33];
  __shared__ float red8[8][32];
  __shared__ float fin[64];
  __shared__ float cvs[64];
  __shared__ float as_l[FF];
  __shared__ float av_l[192];
  __shared__ float inv_l[VV];
  __shared__ float hsn[FF];
  __shared__ float hsv_l[VV];
  __shared__ float redn[256];

  const int r   = blockIdx.x;
  const int tid = threadIdx.x;

  if (tid < 64) {
    float a = 0.f;
    #pragma unroll 8
    for (int f = 0; f < FF; ++f) a += embed[f] * Wsv0[f * VV + tid];
    cvs[tid] = a;
  }

  float wr1[RH];
  #pragma unroll
  for (int hh = 0; hh < RH; ++hh) wr1[hh] = Wr1[hh];

  const float xr0 = x[r * 3 + 0], xr1 = x[r * 3 + 1], xr2 = x[r * 3 + 2];

  float acc[64];
  #pragma unroll
  for (int i = 0; i < 64; ++i) acc[i] = 0.f;

  #pragma unroll
  for (int ss = 0; ss < 3; ++ss) {
    const int s = tid + ss * 256;
    const float vx = x[s * 3 + 0] - xr0;
    const float vy = x[s * 3 + 1] - xr1;
    const float vz = x[s * 3 + 2] - xr2;
    const float d  = __builtin_amdgcn_sqrtf(vx * vx + vy * vy + vz * vz);
    const float iv = __builtin_amdgcn_rcpf(d + 1e-8f);
    const float ux = vx * iv, uy = vy * iv, uz = vz * iv;
    #pragma unroll
    for (int h = 0; h < RH; ++h) {
      const float rf = silu_f(d * wr1[h]);
      acc[h * 4 + 0] += rf;
      acc[h * 4 + 1] += rf * ux;
      acc[h * 4 + 2] += rf * uy;
      acc[h * 4 + 3] += rf * uz;
    }
  }

  {
    #pragma unroll
    for (int i = 0; i < 32; ++i) accT[tid * 33 + i] = acc[i];
    __syncthreads();
    {
      const int j2 = tid & 31, q2 = tid >> 5;
      float a0 = 0.f, a1 = 0.f;
      #pragma unroll 8
      for (int rr = 0; rr < 32; rr += 2) {
        a0 += accT[(q2 * 32 + rr) * 33 + j2];
        a1 += accT[(q2 * 32 + rr + 1) * 33 + j2];
      }
      red8[q2][j2] = a0 + a1;
    }
    __syncthreads();
    if (tid < 32) {
      float a = 0.f;
      #pragma unroll
      for (int g = 0; g < 8; ++g) a += red8[g][tid];
      fin[tid] = a;
    }
    __syncthreads();

    #pragma unroll
    for (int i = 0; i < 32; ++i) accT[tid * 33 + i] = acc[32 + i];
    __syncthreads();
    {
      const int j2 = tid & 31, q2 = tid >> 5;
      float a0 = 0.f, a1 = 0.f;
      #pragma unroll 8
      for (int rr = 0; rr < 32; rr += 2) {
        a0 += accT[(q2 * 32 + rr) * 33 + j2];
        a1 += accT[(q2 * 32 + rr + 1) * 33 + j2];
      }
      red8[q2][j2] = a0 + a1;
    }
    __syncthreads();
    if (tid < 32) {
      float a = 0.f;
      #pragma unroll
      for (int g = 0; g < 8; ++g) a += red8[g][tid];
      fin[32 + tid] = a;
    }
    __syncthreads();
  }

  if (tid < FF) {
    float a = 0.f;
    #pragma unroll
    for (int hh = 0; hh < RH; ++hh) a += fin[hh * 4] * Wr2s[hh * FF + tid];
    as_l[tid] = a * embed[tid] * (1.0f / 64.0f);
  }
  if (tid < 192) {
    const int v = tid / 3, d = tid - v * 3;
    float a = 0.f;
    #pragma unroll
    for (int hh = 0; hh < RH; ++hh) a += fin[hh * 4 + 1 + d] * Wr2v[hh * VV + v];
    av_l[tid] = a * cvs[v] * (1.0f / 64.0f);
  }
  __syncthreads();

  if (tid < VV) {
    const float a0 = av_l[tid * 3 + 0], a1 = av_l[tid * 3 + 1], a2 = av_l[tid * 3 + 2];
    inv_l[tid] = a0 * a0 + a1 * a1 + a2 * a2;
  }
  __syncthreads();

  {
    const int f = tid & 127, part = tid >> 7;
    float a = 0.f;
    const float* wp = Wss + (part * 64) * FF + f;
    #pragma unroll 8
    for (int kk = 0; kk < 64; ++kk) a += as_l[part * 64 + kk] * wp[kk * FF];
    const float* vp = Wvs + (part * 32) * FF + f;
    #pragma unroll 8
    for (int vv = 0; vv < 32; ++vv) a += inv_l[part * 32 + vv] * vp[vv * FF];
    redn[part * 128 + f] = a;
  }
  __syncthreads();

  if (tid < FF) {
    const float hnew = silu_f(embed[tid] + redn[tid] + redn[128 + tid]);
    hs[(size_t)r * FF + tid] = hnew;
    hsn[tid] = hnew;
  }
  if (tid < 192) {
    const int w = tid / 3, d = tid - w * 3;
    float a = 0.f;
    #pragma unroll 8
    for (int v = 0; v < VV; ++v) a += av_l[v * 3 + d] * Wvv[v * VV + w];
    hv[(size_t)r * 192 + tid] = a;
  }
  __syncthreads();

  {
    const int v = tid & 63, part = tid >> 6;
    float a = 0.f;
    const float* wp = Wsv1 + (part * 32) * VV + v;
    #pragma unroll 8
    for (int f = 0; f < 32; ++f) a += hsn[part * 32 + f] * wp[f * VV];
    redn[tid] = a;
  }
  __syncthreads();
  if (tid < VV)
    hsv_l[tid] = redn[tid] + redn[64 + tid] + redn[128 + tid] + redn[192 + tid];
  __syncthreads();

  // ---- fused B emission for layer 1 ----
  {
    const float* W2s = Wr2s + RH * FF;
    const float* W2v = Wr2v + RH * VV;
    const int s     = r;
    const int kstep = s >> 1;
    const int lbase = (s & 1) << 5;
    const float xs0 = x[s * 3 + 0], xs1 = x[s * 3 + 1], xs2 = x[s * 3 + 2];

    #pragma unroll
    for (int k = 0; k < 3; ++k) {
      const int item  = tid + k * 256;
      const int ntile = item >> 5;
      const int li    = item & 31;
      const int lane  = lbase + li;
      const int hb    = ((li >> 4) & 1) * 8;

      bf16x8_t o;
      if (ntile < NT_S) {
        const int f = ntile * 16 + (li & 15);
        const float hf = hsn[f] * 0.015625f;
        #pragma unroll
        for (int e = 0; e < 8; ++e)
          o[e] = f2bf(hf * W2s[(hb + e) * FF + f]);
        *(bf16x8_t*)&Bs[((size_t)(kstep * NT_S + ntile) * 64 + lane) * 8] = o;
      } else {
        const int nt2 = ntile - NT_S;
        const int n   = nt2 * 16 + (li & 15);
        int v; float scale;
        if (n < 192) {
          const int dd = n >> 6; v = n & 63;
          const float xd = (dd == 0) ? xs0 : ((dd == 1) ? xs1 : xs2);
          scale = xd * hsv_l[v] * 0.015625f;
        } else {
          v = n - 192; scale = hsv_l[v] * 0.015625f;
        }
        #pragma unroll
        for (int e = 0; e < 8; ++e)
          o[e] = f2bf(scale * W2v[(hb + e) * VV + v]);
        *(bf16x8_t*)&Bv[((size_t)(kstep * NT_V + nt2) * 64 + lane) * 8] = o;
      }
    }
  }
}

// ---------------------------------------------------------------------------
// edge GEMM (R17 verbatim): SPLITK=24, grid = 24x24 = 576. M=32/block,
// combined kinds, bf16 partial output.
// ---------------------------------------------------------------------------
__global__ __launch_bounds__(256) void edge_gemm(
    const float* __restrict__ x,
    const unsigned short* __restrict__ Bs,
    const unsigned short* __restrict__ Bv,
    const float* __restrict__ Wr1,    // [16] layer-1 slice
    unsigned short* __restrict__ Ps,  // [SPLITK][768][128] bf16
    unsigned short* __restrict__ Pv)  // [SPLITK][768][256] bf16
{
  __shared__ unsigned short A_lds[4 * 2 * 64 * 8];  // 8 KB
  __shared__ unsigned short G_lds[4 * 2 * 64 * 8];  // 8 KB

  // bijective XCD swizzle: 576 = 8 * 72; xcd owns kc in [3*xcd, 3*xcd+2]
  const int wg = ((blockIdx.x & 7) * 72) + (blockIdx.x >> 3);
  const int kc = wg / MB_N;
  const int mb = wg - kc * MB_N;

  const int tid  = threadIdx.x;
  const int lane = tid & 63;
  const int w    = tid >> 6;

  float wr1[RH];
  #pragma unroll
  for (int h = 0; h < RH; ++h) wr1[h] = Wr1[h];

  const int r_local = tid & 31;
  const int s_ii    = tid >> 5;
  const int r = mb * 32 + r_local;
  const int mt_w  = r_local >> 4;
  const int ks_w  = s_ii >> 1;
  const int lane0 = (r_local & 15) + ((s_ii & 1) << 5);

  const float xr0 = x[r * 3 + 0], xr1 = x[r * 3 + 1], xr2 = x[r * 3 + 2];
  float sx[NITER], sy[NITER], sz[NITER];
  #pragma unroll
  for (int it = 0; it < NITER; ++it) {
    const int s = kc * SEND_PER_KC + it * 8 + s_ii;
    sx[it] = x[s * 3 + 0]; sy[it] = x[s * 3 + 1]; sz[it] = x[s * 3 + 2];
  }

  f32x4 accS[4], accV[8];
  #pragma unroll
  for (int i = 0; i < 4; ++i) accS[i] = (f32x4){0.f, 0.f, 0.f, 0.f};
  #pragma unroll
  for (int i = 0; i < 8; ++i) accV[i] = (f32x4){0.f, 0.f, 0.f, 0.f};

  for (int it = 0; it < NITER; ++it) {
    {
      const float vx = sx[it] - xr0;
      const float vy = sy[it] - xr1;
      const float vz = sz[it] - xr2;
      const float dd = __builtin_amdgcn_sqrtf(vx * vx + vy * vy + vz * vz);
      const float iv = __builtin_amdgcn_rcpf(dd + 1e-8f);
      float sv[RH];
      #pragma unroll
      for (int h = 0; h < RH; ++h) sv[h] = silu_f(dd * wr1[h]);
      bf16x8_t o0, o1, g0, g1;
      #pragma unroll
      for (int h = 0; h < 8; ++h) {
        o0[h] = f2bf(sv[h]);
        o1[h] = f2bf(sv[h + 8]);
        g0[h] = f2bf(sv[h] * iv);
        g1[h] = f2bf(sv[h + 8] * iv);
      }
      const int off0 = ((ks_w * 2 + mt_w) * 64 + lane0) * 8;
      *(bf16x8_t*)&A_lds[off0]       = o0;
      *(bf16x8_t*)&A_lds[off0 + 128] = o1;
      *(bf16x8_t*)&G_lds[off0]       = g0;
      *(bf16x8_t*)&G_lds[off0 + 128] = g1;
    }
    __syncthreads();

    const int kgb = kc * (SEND_PER_KC / 2) + it * 4;
    #pragma unroll
    for (int ks = 0; ks < 4; ++ks) {
      const bf16x8_t b0 =
          *(const bf16x8_t*)&Bs[((size_t)((kgb + ks) * NT_S + 2 * w) * 64 + lane) * 8];
      const bf16x8_t b1 =
          *(const bf16x8_t*)&Bs[((size_t)((kgb + ks) * NT_S + 2 * w + 1) * 64 + lane) * 8];
      bf16x8_t bv[4];
      #pragma unroll
      for (int j = 0; j < 4; ++j)
        bv[j] = *(const bf16x8_t*)&Bv[((size_t)((kgb + ks) * NT_V + 4 * w + j) * 64 + lane) * 8];
      #pragma unroll
      for (int mt = 0; mt < 2; ++mt) {
        const int aoff = ((ks * 2 + mt) * 64 + lane) * 8;
        const bf16x8_t a  = *(const bf16x8_t*)&A_lds[aoff];
        const bf16x8_t ag = *(const bf16x8_t*)&G_lds[aoff];
        accS[mt * 2 + 0] = __builtin_amdgcn_mfma_f32_16x16x32_bf16(a, b0, accS[mt * 2 + 0], 0, 0, 0);
        accS[mt * 2 + 1] = __builtin_amdgcn_mfma_f32_16x16x32_bf16(a, b1, accS[mt * 2 + 1], 0, 0, 0);
        #pragma unroll
        for (int j = 0; j < 4; ++j)
          accV[mt * 4 + j] = __builtin_amdgcn_mfma_f32_16x16x32_bf16(ag, bv[j], accV[mt * 4 + j], 0, 0, 0);
      }
    }
    __syncthreads();
  }

  const int rowq = (lane >> 4) << 2;
  #pragma unroll
  for (int j = 0; j < 2; ++j) {
    const int col = (2 * w + j) * 16 + (lane & 15);
    #pragma unroll
    for (int mt = 0; mt < 2; ++mt) {
      #pragma unroll
      for (int reg = 0; reg < 4; ++reg) {
        const int row = mb * 32 + mt * 16 + rowq + reg;
        Ps[((size_t)kc * NN + row) * FF + col] =
            (unsigned short)f2bf(accS[mt * 2 + j][reg]);
      }
    }
  }
  #pragma unroll
  for (int j = 0; j < 4; ++j) {
    const int col = (4 * w + j) * 16 + (lane & 15);
    #pragma unroll
    for (int mt = 0; mt < 2; ++mt) {
      #pragma unroll
      for (int reg = 0; reg < 4; ++reg) {
        const int row = mb * 32 + mt * 16 + rowq + reg;
        Pv[((size_t)kc * NN + row) * 256 + col] =
            (unsigned short)f2bf(accV[mt * 4 + j][reg]);
      }
    }
  }
}

// ---------------------------------------------------------------------------
// final kernel (R17 verbatim): node1 (bf16 partial reduce) + readout fused.
// ---------------------------------------------------------------------------
__global__ __launch_bounds__(512) void final_kernel(
    const unsigned short* __restrict__ Ps,  // [SPLITK][768][128] bf16
    const unsigned short* __restrict__ Pv,  // [SPLITK][768][256] bf16
    const float* __restrict__ x,
    const float* __restrict__ hs,       // layer-0 output
    const float* __restrict__ hv,       // layer-0 output
    const float* __restrict__ Wss,      // layer-1
    const float* __restrict__ Wvs,      // layer-1
    const float* __restrict__ Wvv,      // layer-1
    const float* __restrict__ Wro_s1,
    const float* __restrict__ Wro_s2,
    const float* __restrict__ Wro_v1,
    const float* __restrict__ Wro_v2,
    float* __restrict__ out)
{
  __shared__ float as_l[FF];
  __shared__ float pvs_l[256];
  __shared__ float av_l[192];
  __shared__ float inv_l[VV];
  __shared__ float hsn[FF];
  __shared__ float hv_l[192];
  __shared__ float red[512];
  __shared__ float red2[384];
  __shared__ float t1[FF];
  __shared__ float tv1[192];
  const int n = blockIdx.x, t = threadIdx.x;

  // fused splitK reduce (bf16 loads)
  if (t < FF) {
    float a = 0.f;
    #pragma unroll
    for (int kc = 0; kc < SPLITK; ++kc)
      a += bf2f(Ps[((size_t)kc * NN + n) * FF + t]);
    as_l[t] = a;
  } else if (t < 384) {
    const int cc = t - 128;
    float a = 0.f;
    #pragma unroll
    for (int kc = 0; kc < SPLITK; ++kc)
      a += bf2f(Pv[((size_t)kc * NN + n) * 256 + cc]);
    pvs_l[cc] = a;
  }
  __syncthreads();

  if (t < VV) {
    const float base = pvs_l[192 + t];
    const float a0 = pvs_l[t]       - x[n * 3 + 0] * base;
    const float a1 = pvs_l[64 + t]  - x[n * 3 + 1] * base;
    const float a2 = pvs_l[128 + t] - x[n * 3 + 2] * base;
    av_l[t * 3 + 0] = a0; av_l[t * 3 + 1] = a1; av_l[t * 3 + 2] = a2;
    inv_l[t] = a0 * a0 + a1 * a1 + a2 * a2;
  }
  __syncthreads();

  // hs partials: 4-way split over K
  {
    const int f = t & 127, part = t >> 7;
    float acc = 0.f;
    const float* wp = Wss + (part * 32) * FF + f;
    #pragma unroll 8
    for (int kk = 0; kk < 32; ++kk) acc += as_l[part * 32 + kk] * wp[kk * FF];
    const float* vp = Wvs + (part * 16) * FF + f;
    #pragma unroll 8
    for (int vv = 0; vv < 16; ++vv) acc += inv_l[part * 16 + vv] * vp[vv * FF];
    red[part * 128 + f] = acc;
  }
  __syncthreads();

  if (t < FF) {
    hsn[t] = silu_f(hs[n * FF + t] + red[t] + red[128 + t] + red[256 + t] + red[384 + t]);
  }
  if (t < 384) {
    const int part = t / 192, j = t - part * 192;
    const int wv = j / 3, d = j - wv * 3;
    float acc = 0.f;
    const float* vp = Wvv + (part * 32) * VV + wv;
    #pragma unroll 8
    for (int v = 0; v < 32; ++v) acc += av_l[(part * 32 + v) * 3 + d] * vp[v * VV];
    red2[part * 192 + j] = acc;
  }
  __syncthreads();

  if (t < 192) hv_l[t] = hv[n * 192 + t] + red2[t] + red2[192 + t];
  __syncthreads();

  // ---- readout, inputs hsn / hv_l ----
  {
    const int f = t & 127, part = t >> 7;
    float acc = 0.f;
    const float* wp = Wro_s1 + (part * 32) * FF + f;
    #pragma unroll 8
    for (int kk = 0; kk < 32; ++kk) acc += hsn[part * 32 + kk] * wp[kk * FF];
    red[part * 128 + f] = acc;
  }
  __syncthreads();
  if (t < FF) t1[t] = silu_f(red[t] + red[128 + t] + red[256 + t] + red[384 + t]);
  if (t < 384) {
    const int part = t / 192, j = t - part * 192;
    const int wv = j / 3, d = j - wv * 3;
    float acc = 0.f;
    const float* vp = Wro_v1 + (part * 32) * VV + wv;
    #pragma unroll 8
    for (int v = 0; v < 32; ++v) acc += hv_l[(part * 32 + v) * 3 + d] * vp[v * VV];
    red2[part * 192 + j] = acc;
  }
  __syncthreads();
  if (t < 192) tv1[t] = red2[t] + red2[192 + t];
  if (t < 256) {
    const int o = t & 63, part = t >> 6;
    float acc = 0.f;
    const float* wp = Wro_s2 + (part * 32) * 64 + o;
    #pragma unroll 8
    for (int f = 0; f < 32; ++f) acc += t1[part * 32 + f] * wp[f * 64];
    red[t] = acc;
  }
  __syncthreads();
  if (t < 64) out[n * 160 + t] = red[t] + red[64 + t] + red[128 + t] + red[192 + t];
  if (t < 192) {
    const int part = t / 96, j = t - part * 96;
    const int w2 = j / 3, d = j - w2 * 3;
    float acc = 0.f;
    const float* vp = Wro_v2 + (part * 32) * 32 + w2;
    #pragma unroll 8
    for (int wv = 0; wv < 32; ++wv) acc += tv1[(part * 32 + wv) * 3 + d] * vp[wv * 32];
    red2[part * 96 + j] = acc;
  }
  __syncthreads();
  if (t < 96) out[n * 160 + 64 + t] = red2[t] + red2[96 + t];
}

// ---------------------------------------------------------------------------
extern "C" void kernel_launch(void* const* d_in, const int* in_sizes, int n_in,
                              void* d_out, int out_size, void* d_ws, size_t ws_size,
                              hipStream_t stream) {
  const float* x      = (const float*)d_in[0];
  const float* embed  = (const float*)d_in[3];
  const float* Wr1    = (const float*)d_in[4];   // [2][1][16]
  const float* Wr2s   = (const float*)d_in[5];   // [2][16][128]
  const float* Wr2v   = (const float*)d_in[6];   // [2][16][64]
  const float* Wsv    = (const float*)d_in[7];   // [2][128][64]
  const float* Wss    = (const float*)d_in[8];   // [2][128][128]
  const float* Wvs    = (const float*)d_in[9];   // [2][64][128]
  const float* Wvv    = (const float*)d_in[10];  // [2][64][64]
  const float* Wro_s1 = (const float*)d_in[11];
  const float* Wro_s2 = (const float*)d_in[12];
  const float* Wro_v1 = (const float*)d_in[13];
  const float* Wro_v2 = (const float*)d_in[14];

  float* ws_f = (float*)d_ws;
  float* hs    = ws_f;                      // 768*128 f32
  float* hv    = hs + NN * FF;              // 768*192 f32
  unsigned short* Ps = (unsigned short*)(hv + NN * 192);       // 24*768*128 bf16
  unsigned short* Pv = Ps + (size_t)SPLITK * NN * FF;          // 24*768*256 bf16
  unsigned short* Bs = Pv + (size_t)SPLITK * NN * 256;         // 12288*128 bf16
  unsigned short* Bv = Bs + (size_t)12288 * 128;               // 12288*256 bf16
  float* out = (float*)d_out;

  // layer 0 (closed form, register moments) + node0 + B emission, fused
  layer0_kernel<<<NN, 256, 0, stream>>>(
      x, Wr1, Wr2s, Wr2v, embed, Wsv, Wss, Wvs, Wvv, Wsv + FF * VV,
      hs, hv, Bs, Bv);

  // layer 1: combined-kind MFMA edge GEMM -> node1+readout fused
  edge_gemm<<<MB_N * SPLITK, 256, 0, stream>>>(
      x, Bs, Bv, Wr1 + RH, Ps, Pv);
  final_kernel<<<NN, 512, 0, stream>>>(
      Ps, Pv, x, hs, hv, Wss + FF * FF, Wvs + VV * FF, Wvv + VV * VV,
      Wro_s1, Wro_s2, Wro_v1, Wro_v2, out);
}